// Round 3
// baseline (3184.135 us; speedup 1.0000x reference)
//
#include <hip/hip_runtime.h>

typedef float f4 __attribute__((ext_vector_type(4)));

#define NE 800000
#define NN 50000
#define LAT 128
#define KE 192
#define FOUT 64

#define XS_E 196   // LDS stride for edge x tile [64][192]
#define XS_N 132   // LDS stride for node x tile [64][128]
#define HS 132     // LDS stride for h tile [64][128]
#define OS 68      // LDS stride for out tile [64][64]
#define OUT_OFF 8448
#define LDS_FLOATS 12800  // 51.2 KB -> 3 blocks/CU

__global__ void zero_kernel(float* __restrict__ p, int n4) {
  int i = blockIdx.x * blockDim.x + threadIdx.x;
  if (i < n4) ((f4*)p)[i] = f4{0.f, 0.f, 0.f, 0.f};
}

__global__ void edge_mlp_kernel(const float* __restrict__ edge_attr,
                                const float* __restrict__ node_attr,
                                const int* __restrict__ eidx,
                                const float* __restrict__ W1,
                                const float* __restrict__ b1,
                                const float* __restrict__ W2,
                                const float* __restrict__ b2,
                                const float* __restrict__ gamma,
                                const float* __restrict__ beta,
                                float* __restrict__ edge_out,
                                float* __restrict__ agg) {
  __shared__ float lds[LDS_FLOATS];
  __shared__ int s_row[64];
  __shared__ int s_col[64];
  const int t = threadIdx.x;
  const long e0 = (long)blockIdx.x * 64;

  if (t < 64) s_row[t] = eidx[e0 + t];
  else if (t < 128) s_col[t - 64] = eidx[NE + e0 + (t - 64)];
  __syncthreads();

  // ---- stage x = [receiver | sender | edge_attr] -> lds[e][0..191] ----
  {
    const int e = t >> 2, q = t & 3;
    const f4* rsrc = (const f4*)(node_attr + (size_t)s_col[e] * 64 + q * 16);
    const f4* ssrc = (const f4*)(node_attr + (size_t)s_row[e] * 64 + q * 16);
    const f4* esrc = (const f4*)(edge_attr + (size_t)(e0 + e) * 64 + q * 16);
    f4* xr = (f4*)&lds[e * XS_E + q * 16];
#pragma unroll
    for (int i = 0; i < 4; i++) xr[i] = rsrc[i];
    f4* xs = (f4*)&lds[e * XS_E + 64 + q * 16];
#pragma unroll
    for (int i = 0; i < 4; i++) xs[i] = ssrc[i];
    f4* xe = (f4*)&lds[e * XS_E + 128 + q * 16];
#pragma unroll
    for (int i = 0; i < 4; i++) xe[i] = esrc[i];
  }
  __syncthreads();

  // ---- layer 1: h = relu(x @ W1 + b1), K=192 -> 128 ----
  const int jg = t & 15, eg = t >> 4;
  const int j0 = jg * 8;
  float acc[4][8];
#pragma unroll
  for (int i = 0; i < 4; i++)
#pragma unroll
    for (int j = 0; j < 8; j++) acc[i][j] = 0.f;

  for (int k = 0; k < KE; k += 4) {
    f4 xv[4];
#pragma unroll
    for (int i = 0; i < 4; i++) xv[i] = *(const f4*)&lds[(eg * 4 + i) * XS_E + k];
    f4 wv[4][2];
#pragma unroll
    for (int kk = 0; kk < 4; kk++) {
      wv[kk][0] = *(const f4*)&W1[(k + kk) * LAT + j0];
      wv[kk][1] = *(const f4*)&W1[(k + kk) * LAT + j0 + 4];
    }
#pragma unroll
    for (int i = 0; i < 4; i++) {
#pragma unroll
      for (int kk = 0; kk < 4; kk++) {
        const float xv_s = xv[i][kk];
#pragma unroll
        for (int j = 0; j < 4; j++) {
          acc[i][j] += xv_s * wv[kk][0][j];
          acc[i][j + 4] += xv_s * wv[kk][1][j];
        }
      }
    }
  }
  __syncthreads();  // all x reads done; h overlays x region

  {
    const f4 bb0 = *(const f4*)&b1[j0];
    const f4 bb1 = *(const f4*)&b1[j0 + 4];
#pragma unroll
    for (int i = 0; i < 4; i++) {
      f4 h0, h1;
#pragma unroll
      for (int j = 0; j < 4; j++) {
        h0[j] = fmaxf(acc[i][j] + bb0[j], 0.f);
        h1[j] = fmaxf(acc[i][j + 4] + bb1[j], 0.f);
      }
      *(f4*)&lds[(eg * 4 + i) * HS + j0] = h0;
      *(f4*)&lds[(eg * 4 + i) * HS + j0 + 4] = h1;
    }
  }
  __syncthreads();

  // ---- layer 2: o = relu(h @ W2 + b2), K=128 -> 64 ----
  const int og = t & 7, eg2 = t >> 3;
  const int o0 = og * 8;
  float acc2[2][8];
#pragma unroll
  for (int i = 0; i < 2; i++)
#pragma unroll
    for (int j = 0; j < 8; j++) acc2[i][j] = 0.f;

  for (int k = 0; k < LAT; k += 4) {
    f4 hv[2];
#pragma unroll
    for (int i = 0; i < 2; i++) hv[i] = *(const f4*)&lds[(eg2 * 2 + i) * HS + k];
    f4 wv[4][2];
#pragma unroll
    for (int kk = 0; kk < 4; kk++) {
      wv[kk][0] = *(const f4*)&W2[(k + kk) * FOUT + o0];
      wv[kk][1] = *(const f4*)&W2[(k + kk) * FOUT + o0 + 4];
    }
#pragma unroll
    for (int i = 0; i < 2; i++) {
#pragma unroll
      for (int kk = 0; kk < 4; kk++) {
        const float hv_s = hv[i][kk];
#pragma unroll
        for (int j = 0; j < 4; j++) {
          acc2[i][j] += hv_s * wv[kk][0][j];
          acc2[i][j + 4] += hv_s * wv[kk][1][j];
        }
      }
    }
  }
  {
    const f4 bb0 = *(const f4*)&b2[o0];
    const f4 bb1 = *(const f4*)&b2[o0 + 4];
#pragma unroll
    for (int i = 0; i < 2; i++) {
      f4 v0, v1;
#pragma unroll
      for (int j = 0; j < 4; j++) {
        v0[j] = fmaxf(acc2[i][j] + bb0[j], 0.f);
        v1[j] = fmaxf(acc2[i][j + 4] + bb1[j], 0.f);
      }
      *(f4*)&lds[OUT_OFF + (eg2 * 2 + i) * OS + o0] = v0;
      *(f4*)&lds[OUT_OFF + (eg2 * 2 + i) * OS + o0 + 4] = v1;
    }
  }
  __syncthreads();

  // ---- LayerNorm + store + scatter-add into agg ----
  {
    const int e = t >> 2, p = t & 3;
    f4 v[4];
#pragma unroll
    for (int i = 0; i < 4; i++)
      v[i] = *(const f4*)&lds[OUT_OFF + e * OS + p * 16 + i * 4];
    float s = 0.f, s2 = 0.f;
#pragma unroll
    for (int i = 0; i < 4; i++)
#pragma unroll
      for (int j = 0; j < 4; j++) {
        s += v[i][j];
        s2 += v[i][j] * v[i][j];
      }
    s += __shfl_xor(s, 1);
    s += __shfl_xor(s, 2);
    s2 += __shfl_xor(s2, 1);
    s2 += __shfl_xor(s2, 2);
    const float mu = s * (1.f / 64.f);
    const float var = s2 * (1.f / 64.f) - mu * mu;
    const float rstd = rsqrtf(var + 1e-5f);
    float* op = edge_out + (size_t)(e0 + e) * 64 + p * 16;
    float* ap = agg + (size_t)s_col[e] * 64 + p * 16;
#pragma unroll
    for (int i = 0; i < 4; i++) {
      const f4 g = *(const f4*)&gamma[p * 16 + i * 4];
      const f4 bt = *(const f4*)&beta[p * 16 + i * 4];
      f4 o;
#pragma unroll
      for (int j = 0; j < 4; j++) o[j] = (v[i][j] - mu) * rstd * g[j] + bt[j];
      *(f4*)&op[i * 4] = o;
#pragma unroll
      for (int j = 0; j < 4; j++) atomicAdd(&ap[i * 4 + j], o[j]);
    }
  }
}

__global__ void node_mlp_kernel(const float* __restrict__ node_attr,
                                const float* __restrict__ agg,
                                const float* __restrict__ W1,
                                const float* __restrict__ b1,
                                const float* __restrict__ W2,
                                const float* __restrict__ b2,
                                const float* __restrict__ gamma,
                                const float* __restrict__ beta,
                                float* __restrict__ node_out) {
  __shared__ float lds[LDS_FLOATS];
  const int t = threadIdx.x;
  const long n0 = (long)blockIdx.x * 64;

  // ---- stage x = [node_attr | agg] -> lds[r][0..127] ----
  {
    const int r = t >> 2, q = t & 3;
    long n = n0 + r;
    if (n >= NN) n = NN - 1;  // clamp loads; stores are guarded
    const f4* src = (q < 2) ? (const f4*)(node_attr + (size_t)n * 64 + q * 32)
                            : (const f4*)(agg + (size_t)n * 64 + (q - 2) * 32);
    f4* xd = (f4*)&lds[r * XS_N + q * 32];
#pragma unroll
    for (int i = 0; i < 8; i++) xd[i] = src[i];
  }
  __syncthreads();

  // ---- layer 1: K=128 -> 128 ----
  const int jg = t & 15, eg = t >> 4;
  const int j0 = jg * 8;
  float acc[4][8];
#pragma unroll
  for (int i = 0; i < 4; i++)
#pragma unroll
    for (int j = 0; j < 8; j++) acc[i][j] = 0.f;

  for (int k = 0; k < LAT; k += 4) {
    f4 xv[4];
#pragma unroll
    for (int i = 0; i < 4; i++) xv[i] = *(const f4*)&lds[(eg * 4 + i) * XS_N + k];
    f4 wv[4][2];
#pragma unroll
    for (int kk = 0; kk < 4; kk++) {
      wv[kk][0] = *(const f4*)&W1[(k + kk) * LAT + j0];
      wv[kk][1] = *(const f4*)&W1[(k + kk) * LAT + j0 + 4];
    }
#pragma unroll
    for (int i = 0; i < 4; i++) {
#pragma unroll
      for (int kk = 0; kk < 4; kk++) {
        const float xv_s = xv[i][kk];
#pragma unroll
        for (int j = 0; j < 4; j++) {
          acc[i][j] += xv_s * wv[kk][0][j];
          acc[i][j + 4] += xv_s * wv[kk][1][j];
        }
      }
    }
  }
  __syncthreads();

  {
    const f4 bb0 = *(const f4*)&b1[j0];
    const f4 bb1 = *(const f4*)&b1[j0 + 4];
#pragma unroll
    for (int i = 0; i < 4; i++) {
      f4 h0, h1;
#pragma unroll
      for (int j = 0; j < 4; j++) {
        h0[j] = fmaxf(acc[i][j] + bb0[j], 0.f);
        h1[j] = fmaxf(acc[i][j + 4] + bb1[j], 0.f);
      }
      *(f4*)&lds[(eg * 4 + i) * HS + j0] = h0;
      *(f4*)&lds[(eg * 4 + i) * HS + j0 + 4] = h1;
    }
  }
  __syncthreads();

  // ---- layer 2: K=128 -> 64 ----
  const int og = t & 7, eg2 = t >> 3;
  const int o0 = og * 8;
  float acc2[2][8];
#pragma unroll
  for (int i = 0; i < 2; i++)
#pragma unroll
    for (int j = 0; j < 8; j++) acc2[i][j] = 0.f;

  for (int k = 0; k < LAT; k += 4) {
    f4 hv[2];
#pragma unroll
    for (int i = 0; i < 2; i++) hv[i] = *(const f4*)&lds[(eg2 * 2 + i) * HS + k];
    f4 wv[4][2];
#pragma unroll
    for (int kk = 0; kk < 4; kk++) {
      wv[kk][0] = *(const f4*)&W2[(k + kk) * FOUT + o0];
      wv[kk][1] = *(const f4*)&W2[(k + kk) * FOUT + o0 + 4];
    }
#pragma unroll
    for (int i = 0; i < 2; i++) {
#pragma unroll
      for (int kk = 0; kk < 4; kk++) {
        const float hv_s = hv[i][kk];
#pragma unroll
        for (int j = 0; j < 4; j++) {
          acc2[i][j] += hv_s * wv[kk][0][j];
          acc2[i][j + 4] += hv_s * wv[kk][1][j];
        }
      }
    }
  }
  {
    const f4 bb0 = *(const f4*)&b2[o0];
    const f4 bb1 = *(const f4*)&b2[o0 + 4];
#pragma unroll
    for (int i = 0; i < 2; i++) {
      f4 v0, v1;
#pragma unroll
      for (int j = 0; j < 4; j++) {
        v0[j] = fmaxf(acc2[i][j] + bb0[j], 0.f);
        v1[j] = fmaxf(acc2[i][j + 4] + bb1[j], 0.f);
      }
      *(f4*)&lds[OUT_OFF + (eg2 * 2 + i) * OS + o0] = v0;
      *(f4*)&lds[OUT_OFF + (eg2 * 2 + i) * OS + o0 + 4] = v1;
    }
  }
  __syncthreads();

  // ---- LayerNorm + store ----
  {
    const int e = t >> 2, p = t & 3;
    f4 v[4];
#pragma unroll
    for (int i = 0; i < 4; i++)
      v[i] = *(const f4*)&lds[OUT_OFF + e * OS + p * 16 + i * 4];
    float s = 0.f, s2 = 0.f;
#pragma unroll
    for (int i = 0; i < 4; i++)
#pragma unroll
      for (int j = 0; j < 4; j++) {
        s += v[i][j];
        s2 += v[i][j] * v[i][j];
      }
    s += __shfl_xor(s, 1);
    s += __shfl_xor(s, 2);
    s2 += __shfl_xor(s2, 1);
    s2 += __shfl_xor(s2, 2);
    const float mu = s * (1.f / 64.f);
    const float var = s2 * (1.f / 64.f) - mu * mu;
    const float rstd = rsqrtf(var + 1e-5f);
    if (n0 + e < NN) {
      float* op = node_out + (size_t)(n0 + e) * 64 + p * 16;
#pragma unroll
      for (int i = 0; i < 4; i++) {
        const f4 g = *(const f4*)&gamma[p * 16 + i * 4];
        const f4 bt = *(const f4*)&beta[p * 16 + i * 4];
        f4 o;
#pragma unroll
        for (int j = 0; j < 4; j++) o[j] = (v[i][j] - mu) * rstd * g[j] + bt[j];
        *(f4*)&op[i * 4] = o;
      }
    }
  }
}

extern "C" void kernel_launch(void* const* d_in, const int* in_sizes, int n_in,
                              void* d_out, int out_size, void* d_ws, size_t ws_size,
                              hipStream_t stream) {
  const float* edge_attr = (const float*)d_in[0];
  const float* node_attr = (const float*)d_in[1];
  const int* eidx = (const int*)d_in[2];
  // d_in[3] = batch (unused)
  const float* eW1 = (const float*)d_in[4];
  const float* eb1 = (const float*)d_in[5];
  const float* eW2 = (const float*)d_in[6];
  const float* eb2 = (const float*)d_in[7];
  const float* eg = (const float*)d_in[8];
  const float* ebt = (const float*)d_in[9];
  const float* nW1 = (const float*)d_in[10];
  const float* nb1 = (const float*)d_in[11];
  const float* nW2 = (const float*)d_in[12];
  const float* nb2 = (const float*)d_in[13];
  const float* ng = (const float*)d_in[14];
  const float* nbt = (const float*)d_in[15];

  float* out_edge = (float*)d_out;
  float* out_node = out_edge + (size_t)NE * 64;
  float* agg = (float*)d_ws;  // [NN][64] accumulator

  const int n4 = NN * 64 / 4;
  zero_kernel<<<(n4 + 255) / 256, 256, 0, stream>>>(agg, n4);
  edge_mlp_kernel<<<NE / 64, 256, 0, stream>>>(edge_attr, node_attr, eidx,
                                               eW1, eb1, eW2, eb2, eg, ebt,
                                               out_edge, agg);
  node_mlp_kernel<<<(NN + 63) / 64, 256, 0, stream>>>(node_attr, agg,
                                                      nW1, nb1, nW2, nb2, ng, nbt,
                                                      out_node);
}